// Round 2
// 1107.033 us; speedup vs baseline: 1.0561x; 1.0561x over previous
//
#include <hip/hip_runtime.h>
#include <stdint.h>

#define D 64
#define DIN 192
#define RDIM 9
#define TILE 64          // edges per tile
#define IST 200          // inp LDS row stride in bf16 elems (400B: b128-alignable, 2-way banks only)
#define HST 72           // h/g LDS row stride in bf16 elems (144B)
#define RST 12           // rbf LDS row stride in floats (48B, 16B-aligned for b128 reads)

typedef short bf16x8 __attribute__((ext_vector_type(8)));
typedef float f32x4 __attribute__((ext_vector_type(4)));

__device__ __forceinline__ unsigned short f2bf(float f) {
    union { float f; unsigned int u; } v; v.f = f;
    unsigned int r = (v.u + 0x7fffu + ((v.u >> 16) & 1u)) >> 16;  // RNE
    return (unsigned short)r;
}
__device__ __forceinline__ float bf2f(unsigned short h) {
    union { unsigned int u; float f; } v; v.u = ((unsigned int)h) << 16;
    return v.f;
}
__device__ __forceinline__ uint2 pack4bf(float4 x) {
    uint2 r;
    r.x = (unsigned int)f2bf(x.x) | ((unsigned int)f2bf(x.y) << 16);
    r.y = (unsigned int)f2bf(x.z) | ((unsigned int)f2bf(x.w) << 16);
    return r;
}
__device__ __forceinline__ float sigmoidf_(float x) { return 1.0f / (1.0f + __expf(-x)); }
__device__ __forceinline__ float siluf_(float x) { return x * sigmoidf_(x); }
__device__ __forceinline__ f32x4 splat4(float v) { f32x4 r; r[0] = v; r[1] = v; r[2] = v; r[3] = v; return r; }

// Epilogue for one mt quadrant (mt must be a literal). Loads are clamped &
// unconditional so the compiler can hoist them; only the store is guarded.
#define EPI(mt) {                                                              \
    _Pragma("unroll")                                                          \
    for (int r = 0; r < 4; ++r) {                                              \
        const int el = (mt) * 16 + quad * 4 + r;                               \
        const int e  = e0 + el;                                                \
        const int ec = e < E ? e : E - 1;                                      \
        const float sv = shw[(size_t)ec * 64 + n];                             \
        const float h2 = siluf_(acc2_h[(mt)][r]);                              \
        const float g2 = sigmoidf_(acc2_g[(mt)][r]);                           \
        const f32x4 ra = *(const f32x4*)&s_rbf[el * RST];                      \
        const f32x4 rb = *(const f32x4*)&s_rbf[el * RST + 4];                  \
        const float r8 = s_rbf[el * RST + 8];                                  \
        float rw = ra[0]*wfw[0] + ra[1]*wfw[1] + ra[2]*wfw[2] + ra[3]*wfw[3]   \
                 + rb[0]*wfw[4] + rb[1]*wfw[5] + rb[2]*wfw[6] + rb[3]*wfw[7]   \
                 + r8*wfw[8];                                                  \
        const float eu = h2 * g2 * rw * sv;                                    \
        if (e < E) {                                                           \
            if (MODE == 0) {                                                   \
                const float ef = bf2f(s_inp[el * IST + 64 + n]);               \
                out_edge[(size_t)e * 64 + n] = ef + eu;                        \
            } else {                                                           \
                atomicAdd(&agg[(size_t)s_dst[el] * 64 + n], eu);               \
            }                                                                  \
        }                                                                      \
    } }

// MODE 0: edge update -> writes new_edge = edge + eu to out_edge
// MODE 1: node messages -> atomicAdd msg into agg[dst]
template<int MODE>
__global__ __launch_bounds__(256, 3) void mlp_kernel(
    const float* __restrict__ node_f,   // [N,64]
    const float* __restrict__ mid_f,    // [E,64]: edge_features (MODE0) or new_edge (MODE1)
    const int*   __restrict__ src,
    const int*   __restrict__ dst,
    const float* __restrict__ rbf,      // [E,9]
    const float* __restrict__ shw,      // [E,64]
    const float* __restrict__ W1,  const float* __restrict__ b1,
    const float* __restrict__ W2,  const float* __restrict__ b2,
    const float* __restrict__ gW1, const float* __restrict__ gb1,
    const float* __restrict__ gW2, const float* __restrict__ gb2,
    const float* __restrict__ wfW,      // [9,64]
    float* __restrict__ out_edge,
    float* __restrict__ agg,
    int E, int ntiles)
{
    __shared__ __align__(16) unsigned short s_inp[TILE * IST];
    __shared__ __align__(16) unsigned short s_h[TILE * HST];
    __shared__ __align__(16) unsigned short s_g[TILE * HST];
    __shared__ __align__(16) float s_rbf[TILE * RST];
    __shared__ int s_dst[TILE];

    const int tid  = threadIdx.x;
    const int lane = tid & 63;
    const int wave = tid >> 6;
    const int l15  = lane & 15;
    const int quad = lane >> 4;
    const int n    = wave * 16 + l15;   // output column this lane owns

    // ---- per-wave weight B-fragments in registers (bf16) ----
    bf16x8 w1f[6], gw1f[6], w2f[2], gw2f[2];
#pragma unroll
    for (int kt = 0; kt < 6; ++kt) {
#pragma unroll
        for (int j = 0; j < 8; ++j) {
            int k = kt * 32 + quad * 8 + j;
            w1f[kt][j]  = (short)f2bf(W1[k * 64 + n]);
            gw1f[kt][j] = (short)f2bf(gW1[k * 64 + n]);
        }
    }
#pragma unroll
    for (int kt = 0; kt < 2; ++kt) {
#pragma unroll
        for (int j = 0; j < 8; ++j) {
            int k = kt * 32 + quad * 8 + j;
            w2f[kt][j]  = (short)f2bf(W2[k * 64 + n]);
            gw2f[kt][j] = (short)f2bf(gW2[k * 64 + n]);
        }
    }
    float wfw[RDIM];
#pragma unroll
    for (int r = 0; r < RDIM; ++r) wfw[r] = wfW[r * 64 + n];
    const float b1n = b1[n], b2n = b2[n], gb1n = gb1[n], gb2n = gb2[n];

    const int grid = gridDim.x;
    int tile = blockIdx.x;

    // ---- pipelined state: tile data packed bf16 in regs, staged to LDS at loop top ----
    uint2 pxi[4], pef[4], pxj[4];
    float rr[3];
    int vidxC = 0;

    // ---------------- prologue: fetch tile 0 sequentially ----------------
    if (tile < ntiles) {
        const int e0p = tile * TILE;
        {
            int p = e0p + (wave << 4) + l15; if (p >= E) p = E - 1;
            if (lane < 16)      vidxC = src[p];
            else if (lane < 32) vidxC = dst[p];
        }
        float4 re[4];
#pragma unroll
        for (int i = 0; i < 4; ++i) {
            const int e  = e0p + (wave << 4) + i * 4 + quad;
            const int ec = e < E ? e : E - 1;
            re[i] = *(const float4*)&mid_f[(size_t)ec * 64 + l15 * 4];
        }
#pragma unroll
        for (int i = 0; i < 4; ++i) pef[i] = pack4bf(re[i]);
        float4 rx[4], rj[4];
#pragma unroll
        for (int i = 0; i < 4; ++i) {
            const int elq = i * 4 + quad;
            const int si  = __shfl(vidxC, elq, 64);
            const int di  = __shfl(vidxC, 16 + elq, 64);
            rx[i] = *(const float4*)&node_f[(size_t)si * 64 + l15 * 4];
            rj[i] = *(const float4*)&node_f[(size_t)di * 64 + l15 * 4];
        }
#pragma unroll
        for (int i = 0; i < 4; ++i) { pxi[i] = pack4bf(rx[i]); pxj[i] = pack4bf(rj[i]); }
#pragma unroll
        for (int j = 0; j < 3; ++j) {
            const int idx = tid + j * 256;
            const int gi  = e0p * RDIM + idx;
            rr[j] = (idx < TILE * RDIM && gi < E * RDIM) ? rbf[gi] : 0.0f;
        }
    }

    for (; tile < ntiles; tile += grid) {
        const int e0  = tile * TILE;
        const int nxt = tile + grid;
        const int ne0 = (nxt < ntiles ? nxt : tile) * TILE;  // clamped: last-iter prefetch is harmless/unused

        __syncthreads();   // B1: previous tile's LDS consumers done

        // ---- write phase: registers -> LDS (no global latency here) ----
#pragma unroll
        for (int i = 0; i < 4; ++i) {
            const int el = (wave << 4) + i * 4 + quad;
            *(uint2*)&s_inp[el * IST +       l15 * 4] = pxi[i];
            *(uint2*)&s_inp[el * IST +  64 + l15 * 4] = pef[i];
            *(uint2*)&s_inp[el * IST + 128 + l15 * 4] = pxj[i];
        }
#pragma unroll
        for (int j = 0; j < 3; ++j) {
            const int idx = tid + j * 256;
            if (idx < TILE * RDIM) s_rbf[(idx / RDIM) * RST + (idx % RDIM)] = rr[j];
        }
        if (MODE == 1 && lane >= 16 && lane < 32) s_dst[(wave << 4) + (lane - 16)] = vidxC;
        __syncthreads();   // B2: tile inputs visible

        // ---- prefetch (next tile): idx + streamed ef rows; covered by stage1, retired before B3 drain ----
        int vidxN = 0;
        {
            int p = ne0 + (wave << 4) + l15; if (p >= E) p = E - 1;
            if (lane < 16)      vidxN = src[p];
            else if (lane < 32) vidxN = dst[p];
        }
        float4 re[4];
#pragma unroll
        for (int i = 0; i < 4; ++i) {
            const int e  = ne0 + (wave << 4) + i * 4 + quad;
            const int ec = e < E ? e : E - 1;
            re[i] = *(const float4*)&mid_f[(size_t)ec * 64 + l15 * 4];
        }

        // ---- stage 1 ----
        f32x4 acc_h[4], acc_g[4];
#pragma unroll
        for (int mt = 0; mt < 4; ++mt) { acc_h[mt] = splat4(b1n); acc_g[mt] = splat4(gb1n); }
#pragma unroll
        for (int kt = 0; kt < 6; ++kt) {
#pragma unroll
            for (int mt = 0; mt < 4; ++mt) {
                const bf16x8 a = *(const bf16x8*)&s_inp[(mt * 16 + l15) * IST + kt * 32 + quad * 8];
                acc_h[mt] = __builtin_amdgcn_mfma_f32_16x16x32_bf16(a, w1f[kt],  acc_h[mt], 0, 0, 0);
                acc_g[mt] = __builtin_amdgcn_mfma_f32_16x16x32_bf16(a, gw1f[kt], acc_g[mt], 0, 0, 0);
            }
        }
#pragma unroll
        for (int mt = 0; mt < 4; ++mt) {
#pragma unroll
            for (int r = 0; r < 4; ++r) {
                int row = mt * 16 + quad * 4 + r;
                s_h[row * HST + n] = f2bf(siluf_(acc_h[mt][r]));
                s_g[row * HST + n] = f2bf(siluf_(acc_g[mt][r]));
            }
        }
        __syncthreads();   // B3: h/g visible (prefetched loads above already retired)

        // pack prefetched ef now (register-only work in the post-barrier bubble)
#pragma unroll
        for (int i = 0; i < 4; ++i) pef[i] = pack4bf(re[i]);

        // ---- stage 2 ----
        f32x4 acc2_h[4], acc2_g[4];
#pragma unroll
        for (int mt = 0; mt < 4; ++mt) { acc2_h[mt] = splat4(b2n); acc2_g[mt] = splat4(gb2n); }
#pragma unroll
        for (int kt = 0; kt < 2; ++kt) {
#pragma unroll
            for (int mt = 0; mt < 4; ++mt) {
                const bf16x8 ah = *(const bf16x8*)&s_h[(mt * 16 + l15) * HST + kt * 32 + quad * 8];
                acc2_h[mt] = __builtin_amdgcn_mfma_f32_16x16x32_bf16(ah, w2f[kt], acc2_h[mt], 0, 0, 0);
                const bf16x8 ag = *(const bf16x8*)&s_g[(mt * 16 + l15) * HST + kt * 32 + quad * 8];
                acc2_g[mt] = __builtin_amdgcn_mfma_f32_16x16x32_bf16(ag, gw2f[kt], acc2_g[mt], 0, 0, 0);
            }
        }

        // ---- gather prefetch group A (next tile xi/xj halves) interleaved with epilogue ----
        int siA0 = __shfl(vidxN, 0 * 4 + quad, 64);
        int siA1 = __shfl(vidxN, 1 * 4 + quad, 64);
        int diA0 = __shfl(vidxN, 16 + 0 * 4 + quad, 64);
        int diA1 = __shfl(vidxN, 16 + 1 * 4 + quad, 64);
        float4 ga0 = *(const float4*)&node_f[(size_t)siA0 * 64 + l15 * 4];
        float4 ga1 = *(const float4*)&node_f[(size_t)siA1 * 64 + l15 * 4];
        float4 ga2 = *(const float4*)&node_f[(size_t)diA0 * 64 + l15 * 4];
        float4 ga3 = *(const float4*)&node_f[(size_t)diA1 * 64 + l15 * 4];

        EPI(0)
        EPI(1)

        pxi[0] = pack4bf(ga0); pxi[1] = pack4bf(ga1);
        pxj[0] = pack4bf(ga2); pxj[1] = pack4bf(ga3);

        // ---- gather prefetch group B + rbf for next tile ----
        int siB0 = __shfl(vidxN, 2 * 4 + quad, 64);
        int siB1 = __shfl(vidxN, 3 * 4 + quad, 64);
        int diB0 = __shfl(vidxN, 16 + 2 * 4 + quad, 64);
        int diB1 = __shfl(vidxN, 16 + 3 * 4 + quad, 64);
        float4 gb0 = *(const float4*)&node_f[(size_t)siB0 * 64 + l15 * 4];
        float4 gb1 = *(const float4*)&node_f[(size_t)siB1 * 64 + l15 * 4];
        float4 gb2 = *(const float4*)&node_f[(size_t)diB0 * 64 + l15 * 4];
        float4 gb3 = *(const float4*)&node_f[(size_t)diB1 * 64 + l15 * 4];
        float rrn0, rrn1, rrn2;
        {
            const int i0 = tid, i1 = tid + 256, i2 = tid + 512;
            const int g0 = ne0 * RDIM + i0, g1 = ne0 * RDIM + i1, g2i = ne0 * RDIM + i2;
            rrn0 = (g0 < E * RDIM) ? rbf[g0] : 0.0f;
            rrn1 = (g1 < E * RDIM) ? rbf[g1] : 0.0f;
            rrn2 = (i2 < TILE * RDIM && g2i < E * RDIM) ? rbf[g2i] : 0.0f;
        }

        EPI(2)
        EPI(3)

        pxi[2] = pack4bf(gb0); pxi[3] = pack4bf(gb1);
        pxj[2] = pack4bf(gb2); pxj[3] = pack4bf(gb3);
        rr[0] = rrn0; rr[1] = rrn1; rr[2] = rrn2;
        vidxC = vidxN;
    }
}

// new_node = node_f + agg @ OW via MFMA, in place over the agg buffer (64 rows / block)
__global__ __launch_bounds__(256) void finalize_kernel(
    const float* __restrict__ node_f, const float* __restrict__ OW,
    float* __restrict__ out_node, int N)
{
    __shared__ __align__(16) unsigned short s_a[64 * HST];

    const int tid  = threadIdx.x;
    const int lane = tid & 63;
    const int wave = tid >> 6;
    const int l15  = lane & 15;
    const int quad = lane >> 4;
    const int n    = wave * 16 + l15;
    const int r0   = blockIdx.x * 64;

    bf16x8 owf[2];
#pragma unroll
    for (int kt = 0; kt < 2; ++kt)
#pragma unroll
        for (int j = 0; j < 8; ++j)
            owf[kt][j] = (short)f2bf(OW[(kt * 32 + quad * 8 + j) * 64 + n]);

    // stage agg rows -> bf16 LDS (thread t covers (row = i*16 + t>>4, cols (t&15)*4..+3))
    const int rb = tid >> 4;
    const int cg = (tid & 15) * 4;
#pragma unroll
    for (int i = 0; i < 4; ++i) {
        int row = i * 16 + rb;
        int gr  = r0 + row;
        int grc = gr < N ? gr : N - 1;
        float4 a4 = *(const float4*)&out_node[(size_t)grc * 64 + cg];
        *(uint2*)&s_a[row * HST + cg] = pack4bf(a4);
    }
    __syncthreads();

    f32x4 acc[4];
#pragma unroll
    for (int mt = 0; mt < 4; ++mt) acc[mt] = splat4(0.0f);
#pragma unroll
    for (int kt = 0; kt < 2; ++kt) {
#pragma unroll
        for (int mt = 0; mt < 4; ++mt) {
            const bf16x8 a = *(const bf16x8*)&s_a[(mt * 16 + l15) * HST + kt * 32 + quad * 8];
            acc[mt] = __builtin_amdgcn_mfma_f32_16x16x32_bf16(a, owf[kt], acc[mt], 0, 0, 0);
        }
    }
#pragma unroll
    for (int mt = 0; mt < 4; ++mt) {
#pragma unroll
        for (int r = 0; r < 4; ++r) {
            int gr = r0 + mt * 16 + quad * 4 + r;
            if (gr < N) out_node[(size_t)gr * 64 + n] = node_f[(size_t)gr * 64 + n] + acc[mt][r];
        }
    }
}

extern "C" void kernel_launch(void* const* d_in, const int* in_sizes, int n_in,
                              void* d_out, int out_size, void* d_ws, size_t ws_size,
                              hipStream_t stream) {
    const float* node_f = (const float*)d_in[0];
    const float* edge_f = (const float*)d_in[1];
    const int*   src    = (const int*)d_in[2];
    const int*   dst    = (const int*)d_in[3];
    const float* rbf    = (const float*)d_in[4];
    const float* snw    = (const float*)d_in[5];
    const float* sew    = (const float*)d_in[6];
    const float* eW1  = (const float*)d_in[7];
    const float* eb1  = (const float*)d_in[8];
    const float* eW2  = (const float*)d_in[9];
    const float* eb2  = (const float*)d_in[10];
    const float* egW1 = (const float*)d_in[11];
    const float* egb1 = (const float*)d_in[12];
    const float* egW2 = (const float*)d_in[13];
    const float* egb2 = (const float*)d_in[14];
    const float* nW1  = (const float*)d_in[15];
    const float* nb1  = (const float*)d_in[16];
    const float* nW2  = (const float*)d_in[17];
    const float* nb2  = (const float*)d_in[18];
    const float* ngW1 = (const float*)d_in[19];
    const float* ngb1 = (const float*)d_in[20];
    const float* ngW2 = (const float*)d_in[21];
    const float* ngb2 = (const float*)d_in[22];
    const float* noW  = (const float*)d_in[23];
    const float* nwf  = (const float*)d_in[24];
    const float* ewf  = (const float*)d_in[25];

    const int N = in_sizes[0] / 64;
    const int E = in_sizes[1] / 64;

    float* out_node = (float*)d_out;                   // doubles as agg accumulator
    float* out_edge = out_node + (size_t)N * 64;

    hipMemsetAsync(out_node, 0, (size_t)N * 64 * sizeof(float), stream);

    const int ntiles = (E + TILE - 1) / TILE;
    const int grid   = 768;   // 3 blocks/CU resident, ~10 tiles/block grid-stride

    mlp_kernel<0><<<grid, 256, 0, stream>>>(
        node_f, edge_f, src, dst, rbf, sew,
        eW1, eb1, eW2, eb2, egW1, egb1, egW2, egb2,
        ewf, out_edge, nullptr, E, ntiles);

    mlp_kernel<1><<<grid, 256, 0, stream>>>(
        node_f, out_edge, src, dst, rbf, snw,
        nW1, nb1, nW2, nb2, ngW1, ngb1, ngW2, ngb2,
        nwf, nullptr, out_node, E, ntiles);

    finalize_kernel<<<(N + 63) / 64, 256, 0, stream>>>(node_f, noW, out_node, N);
}

// Round 3
// 1053.721 us; speedup vs baseline: 1.1095x; 1.0506x over previous
//
#include <hip/hip_runtime.h>
#include <stdint.h>

#define D 64
#define DIN 192
#define RDIM 9
#define TILE 64          // edges per tile
#define IST 200          // inp LDS row stride in bf16 elems (400B: b128-alignable, 2-way banks only)
#define HST 72           // h/g LDS row stride in bf16 elems (144B)
#define RST 12           // rbf LDS row stride in floats (48B, 16B-aligned for b128 reads)

typedef short bf16x8 __attribute__((ext_vector_type(8)));
typedef float f32x4 __attribute__((ext_vector_type(4)));

__device__ __forceinline__ unsigned short f2bf(float f) {
    union { float f; unsigned int u; } v; v.f = f;
    unsigned int r = (v.u + 0x7fffu + ((v.u >> 16) & 1u)) >> 16;  // RNE
    return (unsigned short)r;
}
__device__ __forceinline__ float bf2f(unsigned short h) {
    union { unsigned int u; float f; } v; v.u = ((unsigned int)h) << 16;
    return v.f;
}
__device__ __forceinline__ uint2 pack4bf(float4 x) {
    uint2 r;
    r.x = (unsigned int)f2bf(x.x) | ((unsigned int)f2bf(x.y) << 16);
    r.y = (unsigned int)f2bf(x.z) | ((unsigned int)f2bf(x.w) << 16);
    return r;
}
__device__ __forceinline__ float sigmoidf_(float x) { return 1.0f / (1.0f + __expf(-x)); }
__device__ __forceinline__ float siluf_(float x) { return x * sigmoidf_(x); }
__device__ __forceinline__ f32x4 splat4(float v) { f32x4 r; r[0] = v; r[1] = v; r[2] = v; r[3] = v; return r; }

// Epilogue for one mt quadrant (mt must be a literal). Loads are clamped &
// unconditional so the compiler can hoist them; only the store is guarded.
#define EPI(mt) {                                                              \
    _Pragma("unroll")                                                          \
    for (int r = 0; r < 4; ++r) {                                              \
        const int el = (mt) * 16 + quad * 4 + r;                               \
        const int e  = e0 + el;                                                \
        const int ec = e < E ? e : E - 1;                                      \
        const float sv = shw[(size_t)ec * 64 + n];                             \
        const float h2 = siluf_(acc2_h[(mt)][r]);                              \
        const float g2 = sigmoidf_(acc2_g[(mt)][r]);                           \
        const f32x4 ra = *(const f32x4*)&s_rbf[el * RST];                      \
        const f32x4 rb = *(const f32x4*)&s_rbf[el * RST + 4];                  \
        const float r8 = s_rbf[el * RST + 8];                                  \
        float rw = ra[0]*wfw[0] + ra[1]*wfw[1] + ra[2]*wfw[2] + ra[3]*wfw[3]   \
                 + rb[0]*wfw[4] + rb[1]*wfw[5] + rb[2]*wfw[6] + rb[3]*wfw[7]   \
                 + r8*wfw[8];                                                  \
        const float eu = h2 * g2 * rw * sv;                                    \
        if (e < E) {                                                           \
            if (MODE == 0) {                                                   \
                const float ef = bf2f(s_inp[el * IST + 64 + n]);               \
                out_edge[(size_t)e * 64 + n] = ef + eu;                        \
            } else {                                                           \
                atomicAdd(&agg[(size_t)s_dst[el] * 64 + n], eu);               \
            }                                                                  \
        }                                                                      \
    } }

// MODE 0: edge update -> writes new_edge = edge + eu to out_edge
// MODE 1: node messages -> atomicAdd msg into agg[dst]
// NOTE: plain __launch_bounds__(256). The (256,3) form empirically drove the
// allocator to the 84-VGPR / 6-waves-per-EU bucket and spilled (FETCH +344MB).
template<int MODE>
__global__ __launch_bounds__(256) void mlp_kernel(
    const float* __restrict__ node_f,   // [N,64]
    const float* __restrict__ mid_f,    // [E,64]: edge_features (MODE0) or new_edge (MODE1)
    const int*   __restrict__ src,
    const int*   __restrict__ dst,
    const float* __restrict__ rbf,      // [E,9]
    const float* __restrict__ shw,      // [E,64]
    const float* __restrict__ W1,  const float* __restrict__ b1,
    const float* __restrict__ W2,  const float* __restrict__ b2,
    const float* __restrict__ gW1, const float* __restrict__ gb1,
    const float* __restrict__ gW2, const float* __restrict__ gb2,
    const float* __restrict__ wfW,      // [9,64]
    float* __restrict__ out_edge,
    float* __restrict__ agg,
    int E, int ntiles)
{
    __shared__ __align__(16) unsigned short s_inp[TILE * IST];
    __shared__ __align__(16) unsigned short s_h[TILE * HST];
    __shared__ __align__(16) unsigned short s_g[TILE * HST];
    __shared__ __align__(16) float s_rbf[TILE * RST];
    __shared__ int s_dst[TILE];

    const int tid  = threadIdx.x;
    const int lane = tid & 63;
    const int wave = tid >> 6;
    const int l15  = lane & 15;
    const int quad = lane >> 4;
    const int n    = wave * 16 + l15;   // output column this lane owns

    // ---- per-wave weight B-fragments in registers (bf16) ----
    bf16x8 w1f[6], gw1f[6], w2f[2], gw2f[2];
#pragma unroll
    for (int kt = 0; kt < 6; ++kt) {
#pragma unroll
        for (int j = 0; j < 8; ++j) {
            int k = kt * 32 + quad * 8 + j;
            w1f[kt][j]  = (short)f2bf(W1[k * 64 + n]);
            gw1f[kt][j] = (short)f2bf(gW1[k * 64 + n]);
        }
    }
#pragma unroll
    for (int kt = 0; kt < 2; ++kt) {
#pragma unroll
        for (int j = 0; j < 8; ++j) {
            int k = kt * 32 + quad * 8 + j;
            w2f[kt][j]  = (short)f2bf(W2[k * 64 + n]);
            gw2f[kt][j] = (short)f2bf(gW2[k * 64 + n]);
        }
    }
    float wfw[RDIM];
#pragma unroll
    for (int r = 0; r < RDIM; ++r) wfw[r] = wfW[r * 64 + n];
    const float b1n = b1[n], b2n = b2[n], gb1n = gb1[n], gb2n = gb2[n];

    const int grid = gridDim.x;
    int tile = blockIdx.x;

    // ---- pipelined state: tile data packed bf16 in regs, staged to LDS at loop top ----
    uint2 pxi[4], pef[4], pxj[4];
    float rr[3];
    int vidxC = 0;

    // ---------------- prologue: fetch tile 0 sequentially ----------------
    if (tile < ntiles) {
        const int e0p = tile * TILE;
        {
            int p = e0p + (wave << 4) + l15; if (p >= E) p = E - 1;
            if (lane < 16)      vidxC = src[p];
            else if (lane < 32) vidxC = dst[p];
        }
        float4 re[4];
#pragma unroll
        for (int i = 0; i < 4; ++i) {
            const int e  = e0p + (wave << 4) + i * 4 + quad;
            const int ec = e < E ? e : E - 1;
            re[i] = *(const float4*)&mid_f[(size_t)ec * 64 + l15 * 4];
        }
#pragma unroll
        for (int i = 0; i < 4; ++i) pef[i] = pack4bf(re[i]);
        float4 rx[4], rj[4];
#pragma unroll
        for (int i = 0; i < 4; ++i) {
            const int elq = i * 4 + quad;
            const int si  = __shfl(vidxC, elq, 64);
            const int di  = __shfl(vidxC, 16 + elq, 64);
            rx[i] = *(const float4*)&node_f[(size_t)si * 64 + l15 * 4];
            rj[i] = *(const float4*)&node_f[(size_t)di * 64 + l15 * 4];
        }
#pragma unroll
        for (int i = 0; i < 4; ++i) { pxi[i] = pack4bf(rx[i]); pxj[i] = pack4bf(rj[i]); }
#pragma unroll
        for (int j = 0; j < 3; ++j) {
            const int idx = tid + j * 256;
            const int gi  = e0p * RDIM + idx;
            rr[j] = (idx < TILE * RDIM && gi < E * RDIM) ? rbf[gi] : 0.0f;
        }
    }

    for (; tile < ntiles; tile += grid) {
        const int e0  = tile * TILE;
        const int nxt = tile + grid;
        const int ne0 = (nxt < ntiles ? nxt : tile) * TILE;  // clamped: last-iter prefetch is harmless/unused

        __syncthreads();   // B1: previous tile's LDS consumers done

        // ---- write phase: registers -> LDS (no global latency here) ----
#pragma unroll
        for (int i = 0; i < 4; ++i) {
            const int el = (wave << 4) + i * 4 + quad;
            *(uint2*)&s_inp[el * IST +       l15 * 4] = pxi[i];
            *(uint2*)&s_inp[el * IST +  64 + l15 * 4] = pef[i];
            *(uint2*)&s_inp[el * IST + 128 + l15 * 4] = pxj[i];
        }
#pragma unroll
        for (int j = 0; j < 3; ++j) {
            const int idx = tid + j * 256;
            if (idx < TILE * RDIM) s_rbf[(idx / RDIM) * RST + (idx % RDIM)] = rr[j];
        }
        if (MODE == 1 && lane >= 16 && lane < 32) s_dst[(wave << 4) + (lane - 16)] = vidxC;
        __syncthreads();   // B2: tile inputs visible

        // ---- prefetch next tile's indices only (1 VGPR live across stage 1/2) ----
        int vidxN = 0;
        {
            int p = ne0 + (wave << 4) + l15; if (p >= E) p = E - 1;
            if (lane < 16)      vidxN = src[p];
            else if (lane < 32) vidxN = dst[p];
        }

        // ---- stage 1 ----
        f32x4 acc_h[4], acc_g[4];
#pragma unroll
        for (int mt = 0; mt < 4; ++mt) { acc_h[mt] = splat4(b1n); acc_g[mt] = splat4(gb1n); }
#pragma unroll
        for (int kt = 0; kt < 6; ++kt) {
#pragma unroll
            for (int mt = 0; mt < 4; ++mt) {
                const bf16x8 a = *(const bf16x8*)&s_inp[(mt * 16 + l15) * IST + kt * 32 + quad * 8];
                acc_h[mt] = __builtin_amdgcn_mfma_f32_16x16x32_bf16(a, w1f[kt],  acc_h[mt], 0, 0, 0);
                acc_g[mt] = __builtin_amdgcn_mfma_f32_16x16x32_bf16(a, gw1f[kt], acc_g[mt], 0, 0, 0);
            }
        }
#pragma unroll
        for (int mt = 0; mt < 4; ++mt) {
#pragma unroll
            for (int r = 0; r < 4; ++r) {
                int row = mt * 16 + quad * 4 + r;
                s_h[row * HST + n] = f2bf(siluf_(acc_h[mt][r]));
                s_g[row * HST + n] = f2bf(siluf_(acc_g[mt][r]));
            }
        }
        __syncthreads();   // B3: h/g visible

        // ---- stage 2 ----
        f32x4 acc2_h[4], acc2_g[4];
#pragma unroll
        for (int mt = 0; mt < 4; ++mt) { acc2_h[mt] = splat4(b2n); acc2_g[mt] = splat4(gb2n); }
#pragma unroll
        for (int kt = 0; kt < 2; ++kt) {
#pragma unroll
            for (int mt = 0; mt < 4; ++mt) {
                const bf16x8 ah = *(const bf16x8*)&s_h[(mt * 16 + l15) * HST + kt * 32 + quad * 8];
                acc2_h[mt] = __builtin_amdgcn_mfma_f32_16x16x32_bf16(ah, w2f[kt], acc2_h[mt], 0, 0, 0);
                const bf16x8 ag = *(const bf16x8*)&s_g[(mt * 16 + l15) * HST + kt * 32 + quad * 8];
                acc2_g[mt] = __builtin_amdgcn_mfma_f32_16x16x32_bf16(ag, gw2f[kt], acc2_g[mt], 0, 0, 0);
            }
        }

        // ---- staggered prefetch groups, one 16-VGPR float4 group in flight at a time ----
        // group A: xi/xj first halves, covered by EPI(0)
        int siA0 = __shfl(vidxN, 0 * 4 + quad, 64);
        int siA1 = __shfl(vidxN, 1 * 4 + quad, 64);
        int diA0 = __shfl(vidxN, 16 + 0 * 4 + quad, 64);
        int diA1 = __shfl(vidxN, 16 + 1 * 4 + quad, 64);
        float4 ga0 = *(const float4*)&node_f[(size_t)siA0 * 64 + l15 * 4];
        float4 ga1 = *(const float4*)&node_f[(size_t)siA1 * 64 + l15 * 4];
        float4 ga2 = *(const float4*)&node_f[(size_t)diA0 * 64 + l15 * 4];
        float4 ga3 = *(const float4*)&node_f[(size_t)diA1 * 64 + l15 * 4];

        EPI(0)

        pxi[0] = pack4bf(ga0); pxi[1] = pack4bf(ga1);
        pxj[0] = pack4bf(ga2); pxj[1] = pack4bf(ga3);

        // group B: xi/xj second halves, covered by EPI(1)
        int siB0 = __shfl(vidxN, 2 * 4 + quad, 64);
        int siB1 = __shfl(vidxN, 3 * 4 + quad, 64);
        int diB0 = __shfl(vidxN, 16 + 2 * 4 + quad, 64);
        int diB1 = __shfl(vidxN, 16 + 3 * 4 + quad, 64);
        float4 gb0 = *(const float4*)&node_f[(size_t)siB0 * 64 + l15 * 4];
        float4 gb1 = *(const float4*)&node_f[(size_t)siB1 * 64 + l15 * 4];
        float4 gb2 = *(const float4*)&node_f[(size_t)diB0 * 64 + l15 * 4];
        float4 gb3 = *(const float4*)&node_f[(size_t)diB1 * 64 + l15 * 4];

        EPI(1)

        pxi[2] = pack4bf(gb0); pxi[3] = pack4bf(gb1);
        pxj[2] = pack4bf(gb2); pxj[3] = pack4bf(gb3);

        // group C: streamed ef rows + rbf, covered by EPI(2)/EPI(3)
        float4 re0, re1, re2, re3;
        {
            const int e0a = ne0 + (wave << 4);
            int ea = e0a + 0 * 4 + quad; ea = ea < E ? ea : E - 1;
            int eb = e0a + 1 * 4 + quad; eb = eb < E ? eb : E - 1;
            int ecx = e0a + 2 * 4 + quad; ecx = ecx < E ? ecx : E - 1;
            int ed = e0a + 3 * 4 + quad; ed = ed < E ? ed : E - 1;
            re0 = *(const float4*)&mid_f[(size_t)ea  * 64 + l15 * 4];
            re1 = *(const float4*)&mid_f[(size_t)eb  * 64 + l15 * 4];
            re2 = *(const float4*)&mid_f[(size_t)ecx * 64 + l15 * 4];
            re3 = *(const float4*)&mid_f[(size_t)ed  * 64 + l15 * 4];
        }
        float rrn0, rrn1, rrn2;
        {
            const int i0 = tid, i1 = tid + 256, i2 = tid + 512;
            const int g0 = ne0 * RDIM + i0, g1 = ne0 * RDIM + i1, g2i = ne0 * RDIM + i2;
            rrn0 = (g0 < E * RDIM) ? rbf[g0] : 0.0f;
            rrn1 = (g1 < E * RDIM) ? rbf[g1] : 0.0f;
            rrn2 = (i2 < TILE * RDIM && g2i < E * RDIM) ? rbf[g2i] : 0.0f;
        }

        EPI(2)
        EPI(3)

        pef[0] = pack4bf(re0); pef[1] = pack4bf(re1);
        pef[2] = pack4bf(re2); pef[3] = pack4bf(re3);
        rr[0] = rrn0; rr[1] = rrn1; rr[2] = rrn2;
        vidxC = vidxN;
    }
}

// new_node = node_f + agg @ OW via MFMA, in place over the agg buffer (64 rows / block)
__global__ __launch_bounds__(256) void finalize_kernel(
    const float* __restrict__ node_f, const float* __restrict__ OW,
    float* __restrict__ out_node, int N)
{
    __shared__ __align__(16) unsigned short s_a[64 * HST];

    const int tid  = threadIdx.x;
    const int lane = tid & 63;
    const int wave = tid >> 6;
    const int l15  = lane & 15;
    const int quad = lane >> 4;
    const int n    = wave * 16 + l15;
    const int r0   = blockIdx.x * 64;

    bf16x8 owf[2];
#pragma unroll
    for (int kt = 0; kt < 2; ++kt)
#pragma unroll
        for (int j = 0; j < 8; ++j)
            owf[kt][j] = (short)f2bf(OW[(kt * 32 + quad * 8 + j) * 64 + n]);

    // stage agg rows -> bf16 LDS (thread t covers (row = i*16 + t>>4, cols (t&15)*4..+3))
    const int rb = tid >> 4;
    const int cg = (tid & 15) * 4;
#pragma unroll
    for (int i = 0; i < 4; ++i) {
        int row = i * 16 + rb;
        int gr  = r0 + row;
        int grc = gr < N ? gr : N - 1;
        float4 a4 = *(const float4*)&out_node[(size_t)grc * 64 + cg];
        *(uint2*)&s_a[row * HST + cg] = pack4bf(a4);
    }
    __syncthreads();

    f32x4 acc[4];
#pragma unroll
    for (int mt = 0; mt < 4; ++mt) acc[mt] = splat4(0.0f);
#pragma unroll
    for (int kt = 0; kt < 2; ++kt) {
#pragma unroll
        for (int mt = 0; mt < 4; ++mt) {
            const bf16x8 a = *(const bf16x8*)&s_a[(mt * 16 + l15) * HST + kt * 32 + quad * 8];
            acc[mt] = __builtin_amdgcn_mfma_f32_16x16x32_bf16(a, owf[kt], acc[mt], 0, 0, 0);
        }
    }
#pragma unroll
    for (int mt = 0; mt < 4; ++mt) {
#pragma unroll
        for (int r = 0; r < 4; ++r) {
            int gr = r0 + mt * 16 + quad * 4 + r;
            if (gr < N) out_node[(size_t)gr * 64 + n] = node_f[(size_t)gr * 64 + n] + acc[mt][r];
        }
    }
}

extern "C" void kernel_launch(void* const* d_in, const int* in_sizes, int n_in,
                              void* d_out, int out_size, void* d_ws, size_t ws_size,
                              hipStream_t stream) {
    const float* node_f = (const float*)d_in[0];
    const float* edge_f = (const float*)d_in[1];
    const int*   src    = (const int*)d_in[2];
    const int*   dst    = (const int*)d_in[3];
    const float* rbf    = (const float*)d_in[4];
    const float* snw    = (const float*)d_in[5];
    const float* sew    = (const float*)d_in[6];
    const float* eW1  = (const float*)d_in[7];
    const float* eb1  = (const float*)d_in[8];
    const float* eW2  = (const float*)d_in[9];
    const float* eb2  = (const float*)d_in[10];
    const float* egW1 = (const float*)d_in[11];
    const float* egb1 = (const float*)d_in[12];
    const float* egW2 = (const float*)d_in[13];
    const float* egb2 = (const float*)d_in[14];
    const float* nW1  = (const float*)d_in[15];
    const float* nb1  = (const float*)d_in[16];
    const float* nW2  = (const float*)d_in[17];
    const float* nb2  = (const float*)d_in[18];
    const float* ngW1 = (const float*)d_in[19];
    const float* ngb1 = (const float*)d_in[20];
    const float* ngW2 = (const float*)d_in[21];
    const float* ngb2 = (const float*)d_in[22];
    const float* noW  = (const float*)d_in[23];
    const float* nwf  = (const float*)d_in[24];
    const float* ewf  = (const float*)d_in[25];

    const int N = in_sizes[0] / 64;
    const int E = in_sizes[1] / 64;

    float* out_node = (float*)d_out;                   // doubles as agg accumulator
    float* out_edge = out_node + (size_t)N * 64;

    hipMemsetAsync(out_node, 0, (size_t)N * 64 * sizeof(float), stream);

    const int ntiles = (E + TILE - 1) / TILE;
    const int grid   = 768;   // 3 blocks/CU resident, ~10 tiles/block grid-stride

    mlp_kernel<0><<<grid, 256, 0, stream>>>(
        node_f, edge_f, src, dst, rbf, sew,
        eW1, eb1, eW2, eb2, egW1, egb1, egW2, egb2,
        ewf, out_edge, nullptr, E, ntiles);

    mlp_kernel<1><<<grid, 256, 0, stream>>>(
        node_f, out_edge, src, dst, rbf, snw,
        nW1, nb1, nW2, nb2, ngW1, ngb1, ngW2, ngb2,
        nwf, nullptr, out_node, E, ntiles);

    finalize_kernel<<<(N + 63) / 64, 256, 0, stream>>>(node_f, noW, out_node, N);
}